// Round 7
// baseline (161.953 us; speedup 1.0000x reference)
//
#include <hip/hip_runtime.h>

// Problem constants (match reference file)
#define B_DIM 512
#define S_DIM 1024
#define NTOK (B_DIM * S_DIM)          // 524288 tokens
#define CHAR_LEN 32
#define MAX_CANDS 4000
#define N_PRIV 8
#define CTX_RATE 0.15f

typedef int vint4 __attribute__((ext_vector_type(4)));  // clang-native 16B vector

// Output layout (concatenated flat, int32):
//   [0*NTOK)   obf_word
//   [1*NTOK)   inp_word (copy)
//   [2*NTOK)   obf_char (NTOK*32)
//   [34*NTOK)  inp_pos (copy)
//   [35*NTOK)  obf_mask (0/1)
//   [36*NTOK)  pri_mask (0/1)
//   [37*NTOK)  cpy_mask (0/1)

__global__ __launch_bounds__(256) void alltag_kernel(
    const int* __restrict__ inp_word,
    const int* __restrict__ inp_pos,
    const int* __restrict__ inp_mask,
    const float* __restrict__ ctx_rand,
    const float* __restrict__ pri_rand,
    const float* __restrict__ cand_u,
    const vint4* __restrict__ lut4,      // [VOCAB][8] vint4
    const int* __restrict__ tgt_table,   // [N_POS][MAX_CANDS]
    const int* __restrict__ counts,      // [N_POS]
    int* __restrict__ out)
{
    // Wave-private 64-token LDS slices: no __syncthreads needed (a wave's DS
    // ops execute in order; zero cross-wave LDS sharing by construction).
    __shared__ int s_ow[256];

    const int tid   = threadIdx.x;
    const int lane  = tid & 63;
    const int wave  = tid >> 6;                  // [0,4)
    const int token = blockIdx.x * 256 + tid;    // 1 lane = 1 token (R4 geom)
    const int wtok0 = token - lane;              // this wave's first token

    // ---- Phase A: coalesced scalars, compute obf_word once per token ------
    int   pos  = __builtin_nontemporal_load(&inp_pos[token]);
    int   word = __builtin_nontemporal_load(&inp_word[token]);
    float cr   = __builtin_nontemporal_load(&ctx_rand[token]);
    float pr   = __builtin_nontemporal_load(&pri_rand[token]);
    float cu   = __builtin_nontemporal_load(&cand_u[token]);
    int   msk  = __builtin_nontemporal_load(&inp_mask[token]);

    bool pri_mask = (pos < N_PRIV);              // priv_pos = arange < N_PRIV
    bool obf = pri_mask ? (pr < 1.0f) : (cr < CTX_RATE);

    int cnt = counts[pos];                       // 160B, L1-resident
    int idx = (int)(cu * (float)cnt);            // JAX trunc semantics
    idx = min(idx, cnt - 1);
    int cdt = tgt_table[pos * MAX_CANDS + idx];  // 640KB, L2-resident
    int ow  = obf ? cdt : word;

    s_ow[wave * 64 + lane] = ow;                 // wave-private slice

    __builtin_nontemporal_store(ow, &out[token]);
    __builtin_nontemporal_store(word, &out[NTOK + token]);
    __builtin_nontemporal_store(pos, &out[(size_t)NTOK * 34 + token]);
    __builtin_nontemporal_store(obf ? 1 : 0, &out[(size_t)NTOK * 35 + token]);
    __builtin_nontemporal_store(pri_mask ? 1 : 0, &out[(size_t)NTOK * 36 + token]);
    bool cpy = (msk != 0) && (word == ow);
    __builtin_nontemporal_store(cpy ? 1 : 0, &out[(size_t)NTOK * 37 + token]);

    // ---- Phase B: 8 independent lut gathers, wave-local (no barrier) ------
    const int sub = lane & 7;            // 16B chunk of the 128B row
    const int grp = lane >> 3;           // [0,8): token slot within octet
    vint4* out_char4 = (vint4*)(out + (size_t)NTOK * 2);

#pragma unroll
    for (int i = 0; i < 8; ++i) {
        int lt = 8 * i + grp;                      // [0,64) in wave slice
        int w  = s_ow[wave * 64 + lt];             // 8-bank broadcast (free)
        int t  = wtok0 + lt;
        vint4 v = lut4[w * 8 + sub];               // random 16B gather
        __builtin_nontemporal_store(v, &out_char4[(size_t)t * 8 + sub]);
    }
}

extern "C" void kernel_launch(void* const* d_in, const int* in_sizes, int n_in,
                              void* d_out, int out_size, void* d_ws, size_t ws_size,
                              hipStream_t stream) {
    const int*   inp_word  = (const int*)  d_in[0];
    const int*   inp_pos   = (const int*)  d_in[2];
    const int*   inp_mask  = (const int*)  d_in[3];
    const float* ctx_rand  = (const float*)d_in[4];
    const float* pri_rand  = (const float*)d_in[5];
    const float* cand_u    = (const float*)d_in[6];
    const vint4* lut4      = (const vint4*)d_in[7];
    const int*   tgt_table = (const int*)  d_in[8];
    const int*   counts    = (const int*)  d_in[9];
    int* out = (int*)d_out;

    const int block = 256;
    const int grid  = NTOK / block;          // 2048 blocks = 8192 waves (full)
    alltag_kernel<<<grid, block, 0, stream>>>(inp_word, inp_pos, inp_mask,
                                              ctx_rand, pri_rand, cand_u,
                                              lut4, tgt_table, counts, out);
}

// Round 8
// 158.480 us; speedup vs baseline: 1.0219x; 1.0219x over previous
//
#include <hip/hip_runtime.h>

// Problem constants (match reference file)
#define B_DIM 512
#define S_DIM 1024
#define NTOK (B_DIM * S_DIM)          // 524288 tokens
#define CHAR_LEN 32
#define MAX_CANDS 4000
#define N_PRIV 8
#define CTX_RATE 0.15f

typedef int vint4 __attribute__((ext_vector_type(4)));  // clang-native 16B vector

// Output layout (concatenated flat, int32):
//   [0*NTOK)   obf_word
//   [1*NTOK)   inp_word (copy)
//   [2*NTOK)   obf_char (NTOK*32)
//   [34*NTOK)  inp_pos (copy)
//   [35*NTOK)  obf_mask (0/1)
//   [36*NTOK)  pri_mask (0/1)
//   [37*NTOK)  cpy_mask (0/1)
//
// Best-measured configuration (R4): 2048 blocks x 256 thr (8192 waves = full
// device occupancy), phase-split with block LDS + one barrier, 8 independent
// 16B lut gathers per thread in Phase B. Variants tested and rejected:
//   - shuffle-broadcast instead of LDS (R5): +3.3 us
//   - 2 tokens/thread, 1024 blocks (R6): +2.2 us (MLP x waves is conserved)
//   - wave-private LDS, no barrier (R7): +2.7 us (the barrier is free)

__global__ __launch_bounds__(256) void alltag_kernel(
    const int* __restrict__ inp_word,
    const int* __restrict__ inp_pos,
    const int* __restrict__ inp_mask,
    const float* __restrict__ ctx_rand,
    const float* __restrict__ pri_rand,
    const float* __restrict__ cand_u,
    const vint4* __restrict__ lut4,      // [VOCAB][8] vint4
    const int* __restrict__ tgt_table,   // [N_POS][MAX_CANDS]
    const int* __restrict__ counts,      // [N_POS]
    int* __restrict__ out)
{
    __shared__ int s_obf_word[256];

    const int tid        = threadIdx.x;
    const int token_base = blockIdx.x * 256;

    // ---------------- Phase A: 1 thread = 1 token (coalesced scalars) ------
    {
        const int token = token_base + tid;
        int   pos  = __builtin_nontemporal_load(&inp_pos[token]);
        int   word = __builtin_nontemporal_load(&inp_word[token]);
        float cr   = __builtin_nontemporal_load(&ctx_rand[token]);
        float pr   = __builtin_nontemporal_load(&pri_rand[token]);
        float cu   = __builtin_nontemporal_load(&cand_u[token]);
        int   msk  = __builtin_nontemporal_load(&inp_mask[token]);

        bool pri_mask = (pos < N_PRIV);              // priv_pos = arange < N_PRIV
        bool obf = pri_mask ? (pr < 1.0f) : (cr < CTX_RATE);

        int cnt = counts[pos];                       // 160B, L1-resident
        int idx = (int)(cu * (float)cnt);            // JAX trunc semantics
        idx = min(idx, cnt - 1);
        int cdt = tgt_table[pos * MAX_CANDS + idx];  // 640KB, L2-resident
        int obf_word = obf ? cdt : word;

        s_obf_word[tid] = obf_word;

        __builtin_nontemporal_store(obf_word, &out[token]);
        __builtin_nontemporal_store(word, &out[NTOK + token]);
        __builtin_nontemporal_store(pos, &out[(size_t)NTOK * 34 + token]);
        __builtin_nontemporal_store(obf ? 1 : 0, &out[(size_t)NTOK * 35 + token]);
        __builtin_nontemporal_store(pri_mask ? 1 : 0, &out[(size_t)NTOK * 36 + token]);
        bool cpy = (msk != 0) && (word == obf_word);
        __builtin_nontemporal_store(cpy ? 1 : 0, &out[(size_t)NTOK * 37 + token]);
    }

    __syncthreads();

    // ---------------- Phase B: 8 lanes/token, 8 independent gathers --------
    {
        const int sub   = tid & 7;       // which 16B chunk of the 128B row
        const int group = tid >> 3;      // [0,32): token group within block
        vint4* out_char4 = (vint4*)(out + (size_t)NTOK * 2);

#pragma unroll
        for (int i = 0; i < 8; ++i) {
            int lt = group + 32 * i;                  // local token [0,256)
            int w  = s_obf_word[lt];                  // LDS broadcast (free)
            vint4 v = lut4[w * 8 + sub];              // random 16B gather
            __builtin_nontemporal_store(
                v, &out_char4[(size_t)(token_base + lt) * 8 + sub]);
        }
    }
}

extern "C" void kernel_launch(void* const* d_in, const int* in_sizes, int n_in,
                              void* d_out, int out_size, void* d_ws, size_t ws_size,
                              hipStream_t stream) {
    const int*   inp_word  = (const int*)  d_in[0];
    const int*   inp_pos   = (const int*)  d_in[2];
    const int*   inp_mask  = (const int*)  d_in[3];
    const float* ctx_rand  = (const float*)d_in[4];
    const float* pri_rand  = (const float*)d_in[5];
    const float* cand_u    = (const float*)d_in[6];
    const vint4* lut4      = (const vint4*)d_in[7];
    const int*   tgt_table = (const int*)  d_in[8];
    const int*   counts    = (const int*)  d_in[9];
    int* out = (int*)d_out;

    const int block = 256;
    const int grid  = NTOK / block;          // 2048 blocks = 8192 waves (full)
    alltag_kernel<<<grid, block, 0, stream>>>(inp_word, inp_pos, inp_mask,
                                              ctx_rand, pri_rand, cand_u,
                                              lut4, tgt_table, counts, out);
}